// Round 2
// baseline (807.620 us; speedup 1.0000x reference)
//
#include <hip/hip_runtime.h>
#include <cstdint>
#include <cstddef>

// Problem constants
#define B_  8
#define N_  4096   // H*W
#define M_  512    // memory slots
#define D_  512    // feature dim (= C)
#define HW_ 4096

typedef unsigned short u16;
typedef unsigned int   u32;
typedef __attribute__((ext_vector_type(8))) __bf16 bf16x8;
typedef __attribute__((ext_vector_type(4))) float  f32x4;

// -------- workspace layout (float offsets), total 143.0 MB --------
// qf_hl  : 0          [B,N,1024] u16  (per row: 512 hi | 512 lo bf16 of l2-normed q)
// score  : 16777216   [B,N,M] f32 raw; after k_softmax_top2 each row becomes
//                     [512 hi | 512 lo] u16 of softmax-over-m (in place)
// qu     : 33554432   [B,M,D] f32
// inv_nrm: 35651584   [B,N]
// s_at   : 35684352   [B,N]  (raw score at argmax = row max)
// colmax : 35717120   [B,M]  (max over n of raw score)
// assign : 35721216   [B,N] int
// keys hi/lo planes live in d_out scratch (out0 first half, rewritten last).
// fp32 qf lives in d_out out3 region (loss_compact overwrites it in K3).

__device__ __forceinline__ u16 f2bf(float x) {
  u32 u = __float_as_uint(x);
  u += 0x7FFFu + ((u >> 16) & 1u);          // RNE
  return (u16)(u >> 16);
}
__device__ __forceinline__ float bf2f(u16 h) {
  return __uint_as_float(((u32)h) << 16);
}

// K0: keys -> hi/lo planes, and transposed hi/lo planes (for the NN concat GEMM)
__global__ __launch_bounds__(256) void k_convert_keys(
    const float* __restrict__ keys, u16* __restrict__ keys_hl,
    u16* __restrict__ keysT_hl) {
  const int m = blockIdx.x;
  const int tid = threadIdx.x;
  for (int d = tid; d < D_; d += 256) {
    const float v = keys[(size_t)m * D_ + d];
    const u16 h = f2bf(v);
    const u16 l = f2bf(v - bf2f(h));
    keys_hl[(size_t)m * 1024 + d] = h;
    keys_hl[(size_t)m * 1024 + 512 + d] = l;
    keysT_hl[(size_t)d * 1024 + m] = h;
    keysT_hl[(size_t)d * 1024 + 512 + m] = l;
  }
}

// K1: l2-normalize over channel + transpose [B,C,N] -> [B,N,(hi|lo)] + fp32 qf
__global__ __launch_bounds__(256) void k_norm_transpose(
    const float* __restrict__ q, u16* __restrict__ qf_hl,
    float* __restrict__ qf32, float* __restrict__ inv_nrm) {
  __shared__ float tile[32][513];
  __shared__ float red[8][32];
  __shared__ float sinv[32];
  const int b = blockIdx.y;
  const int n0 = blockIdx.x * 32;
  const int tid = threadIdx.x;
  const int tx = tid & 31, ty = tid >> 5;
  const float* qb = q + (size_t)b * D_ * HW_ + n0;
  float ss = 0.f;
  for (int c = ty; c < D_; c += 8) {
    const float v = qb[(size_t)c * HW_ + tx];
    tile[tx][c] = v;
    ss += v * v;
  }
  red[ty][tx] = ss;
  __syncthreads();
  if (ty == 0) {
    float s = 0.f;
#pragma unroll
    for (int r = 0; r < 8; ++r) s += red[r][tx];
    const float inv = 1.0f / fmaxf(sqrtf(s), 1e-12f);
    sinv[tx] = inv;
    inv_nrm[b * N_ + n0 + tx] = inv;
  }
  __syncthreads();
  u16* qfb = qf_hl + ((size_t)b * N_ + n0) * 1024;
  float* q32b = qf32 + ((size_t)b * N_ + n0) * D_;
  for (int i = tid; i < 32 * 256; i += 256) {
    const int nl = i >> 8, c2 = (i & 255) << 1;
    const float va = tile[nl][c2] * sinv[nl];
    const float vb = tile[nl][c2 + 1] * sinv[nl];
    const u16 ha = f2bf(va), hb = f2bf(vb);
    const u16 la = f2bf(va - bf2f(ha)), lb = f2bf(vb - bf2f(hb));
    u32* qr = (u32*)(qfb + (size_t)nl * 1024);
    qr[c2 >> 1] = (u32)ha | ((u32)hb << 16);
    qr[256 + (c2 >> 1)] = (u32)la | ((u32)lb << 16);
    *(float2*)&q32b[(size_t)nl * D_ + c2] = make_float2(va, vb);
  }
}

// K2/K7b: split-bf16 MFMA GEMM.  C = (Ah+Al)(Bh+Bl)^T ~= AhBh + AhBl + AlBh.
// A: [rows][512 hi | 512 lo] u16, rows indexed bb*N_+n.  B: [512 rows][hi|lo].
// EPI=0: C row-major fp32 [B*N][M] (score).  EPI=1: transposed write into
// out0 channels 512..1023 via LDS tile.
template <int EPI>
__global__ __launch_bounds__(256) void k_gemm_split(
    const u16* __restrict__ A, const u16* __restrict__ Bg,
    float* __restrict__ C) {
  // XCD-aware mapping: xcd = id&7 owns one batch (32 n-panels x 4 col-tiles),
  // so the 4 col-tiles sharing an A-panel hit the same XCD L2.
  const int g = blockIdx.x;
  const int xcd = g & 7;
  const int s = g >> 3;
  const int panel = xcd * 32 + (s >> 2);   // 0..255
  const int bb = panel >> 5;               // batch
  const int n0 = (panel & 31) * 128;
  const int c0 = (s & 3) * 128;

  const int tid = threadIdx.x;
  const int lane = tid & 63;
  const int wave = tid >> 6;
  const int wr = wave >> 1, wc = wave & 1;
  const int fr = lane & 15;                // frag row (A) / col (B)
  const int kg = lane >> 4;                // k-group 0..3

  __shared__ union __align__(16) {
    u16  st[2][2][128][40];  // [A/B][hi/lo][row][k, padded to 40 (80B: 2-way ok)]
    float tc[64][129];       // EPI=1 transpose tile
  } sh;

  f32x4 acc[4][4] = {};

  const int srow = tid >> 1;   // 0..127 staged row
  const int shf = tid & 1;     // hi/lo plane
  const u16* ga = A + ((size_t)bb * N_ + n0 + srow) * 1024 + shf * 512;
  const u16* gb = Bg + ((size_t)(c0 + srow)) * 1024 + shf * 512;

  uint4 pa0 = *(const uint4*)(ga + 0),  pa1 = *(const uint4*)(ga + 8);
  uint4 pa2 = *(const uint4*)(ga + 16), pa3 = *(const uint4*)(ga + 24);
  uint4 pb0 = *(const uint4*)(gb + 0),  pb1 = *(const uint4*)(gb + 8);
  uint4 pb2 = *(const uint4*)(gb + 16), pb3 = *(const uint4*)(gb + 24);

  for (int k0 = 0; k0 < 512; k0 += 32) {
    __syncthreads();
    *(uint4*)&sh.st[0][shf][srow][0]  = pa0;
    *(uint4*)&sh.st[0][shf][srow][8]  = pa1;
    *(uint4*)&sh.st[0][shf][srow][16] = pa2;
    *(uint4*)&sh.st[0][shf][srow][24] = pa3;
    *(uint4*)&sh.st[1][shf][srow][0]  = pb0;
    *(uint4*)&sh.st[1][shf][srow][8]  = pb1;
    *(uint4*)&sh.st[1][shf][srow][16] = pb2;
    *(uint4*)&sh.st[1][shf][srow][24] = pb3;
    __syncthreads();
    if (k0 + 32 < 512) {  // prefetch next K-slice; hides HBM under the MFMAs
      const u16* gan = ga + k0 + 32;
      const u16* gbn = gb + k0 + 32;
      pa0 = *(const uint4*)(gan + 0);  pa1 = *(const uint4*)(gan + 8);
      pa2 = *(const uint4*)(gan + 16); pa3 = *(const uint4*)(gan + 24);
      pb0 = *(const uint4*)(gbn + 0);  pb1 = *(const uint4*)(gbn + 8);
      pb2 = *(const uint4*)(gbn + 16); pb3 = *(const uint4*)(gbn + 24);
    }
    bf16x8 ah[4], al[4], bh[4], bl[4];
#pragma unroll
    for (int i = 0; i < 4; ++i) {
      ah[i] = *(const bf16x8*)&sh.st[0][0][wr * 64 + i * 16 + fr][kg * 8];
      al[i] = *(const bf16x8*)&sh.st[0][1][wr * 64 + i * 16 + fr][kg * 8];
      bh[i] = *(const bf16x8*)&sh.st[1][0][wc * 64 + i * 16 + fr][kg * 8];
      bl[i] = *(const bf16x8*)&sh.st[1][1][wc * 64 + i * 16 + fr][kg * 8];
    }
#pragma unroll
    for (int i = 0; i < 4; ++i)
#pragma unroll
      for (int j = 0; j < 4; ++j) {
        acc[i][j] = __builtin_amdgcn_mfma_f32_16x16x32_bf16(ah[i], bh[j],
                                                            acc[i][j], 0, 0, 0);
        acc[i][j] = __builtin_amdgcn_mfma_f32_16x16x32_bf16(ah[i], bl[j],
                                                            acc[i][j], 0, 0, 0);
        acc[i][j] = __builtin_amdgcn_mfma_f32_16x16x32_bf16(al[i], bh[j],
                                                            acc[i][j], 0, 0, 0);
      }
  }

  if (EPI == 0) {
    float* Cb = C + ((size_t)bb * N_ + n0 + wr * 64) * M_ + c0 + wc * 64;
#pragma unroll
    for (int i = 0; i < 4; ++i)
#pragma unroll
      for (int j = 0; j < 4; ++j)
#pragma unroll
        for (int r = 0; r < 4; ++r)
          Cb[(size_t)(i * 16 + kg * 4 + r) * M_ + j * 16 + fr] = acc[i][j][r];
  } else {
#pragma unroll
    for (int half = 0; half < 2; ++half) {
      __syncthreads();
      if (wc == half) {
#pragma unroll
        for (int i = 0; i < 4; ++i)
#pragma unroll
          for (int j = 0; j < 4; ++j)
#pragma unroll
            for (int r = 0; r < 4; ++r)
              sh.tc[j * 16 + fr][wr * 64 + i * 16 + kg * 4 + r] = acc[i][j][r];
      }
      __syncthreads();
      float* ob = C + ((size_t)bb * 1024 + 512 + c0 + half * 64) * (size_t)HW_ + n0;
      for (int t = tid; t < 64 * 128; t += 256) {
        const int dl = t >> 7, nl = t & 127;
        ob[(size_t)dl * HW_ + nl] = sh.tc[dl][nl];
      }
    }
  }
}

// K4: colmax[b][m] = max_n score[b][n][m]  (raw scores; runs before K3)
__global__ __launch_bounds__(256) void k_colmax(
    const float* __restrict__ score, float* __restrict__ colmax) {
  const int b = blockIdx.y, m0 = blockIdx.x * 32;
  const int tid = threadIdx.x, tx = tid & 31, ty = tid >> 5;
  const float* sb = score + (size_t)b * N_ * M_ + m0 + tx;
  float mx = -1e30f;
  for (int n = ty; n < N_; n += 8) mx = fmaxf(mx, sb[(size_t)n * M_]);
  __shared__ float red[8][33];
  red[ty][tx] = mx;
  __syncthreads();
  if (ty == 0) {
#pragma unroll
    for (int r = 1; r < 8; ++r) mx = fmaxf(mx, red[r][tx]);
    colmax[b * M_ + m0 + tx] = mx;
  }
}

// K3: per (b,n) row: approx top-2 from MFMA scores, then EXACT fp32 rescue of
//     the selection (recompute dot products for all candidates within a margin
//     of the approx top-2; pick top-2 with tie-lower-index). Softmax over m
//     written in place as bf16 hi|lo planes, triplet losses from fp32 qf,
//     s_at(=approx score at exact argmax), assign(=exact argmax).
//     qf32row aliases out3 (loss_compact): read fully into LDS before overwrite.
__global__ __launch_bounds__(256) void k_softmax_top2(
    float* __restrict__ score, const float* __restrict__ keys,
    float* __restrict__ out2, float* out3, float* __restrict__ out4,
    float* __restrict__ s_at, int* __restrict__ assign) {
  const int bn = blockIdx.x;
  const int tid = threadIdx.x;
  float* row = score + (size_t)bn * M_;
  float* lrow = out3 + (size_t)bn * D_;   // fp32 qf on entry; loss on exit
  __shared__ float sq[512];
  __shared__ float sv1[256], sv2[256];
  __shared__ int   si1[256], si2[256];
  __shared__ int   cand[48];
  __shared__ float cex[48];
  __shared__ int   ccnt;
  __shared__ int   sel1, sel2;
  __shared__ float ssat;
  sq[tid] = lrow[tid];
  sq[tid + 256] = lrow[tid + 256];
  if (tid == 0) ccnt = 0;
  const float v0 = row[tid];
  const float v1 = row[tid + 256];
  float t1v, t2v; int t1i, t2i;
  if (v0 >= v1) { t1v = v0; t1i = tid;       t2v = v1; t2i = tid + 256; }
  else          { t1v = v1; t1i = tid + 256; t2v = v0; t2i = tid; }
  sv1[tid] = t1v; si1[tid] = t1i; sv2[tid] = t2v; si2[tid] = t2i;
  __syncthreads();
  for (int s = 128; s > 0; s >>= 1) {
    if (tid < s) {
      const float a1 = sv1[tid];     const int a1i = si1[tid];
      const float a2 = sv2[tid];     const int a2i = si2[tid];
      const float b1 = sv1[tid + s]; const int b1i = si1[tid + s];
      const float b2 = sv2[tid + s]; const int b2i = si2[tid + s];
      if (b1 > a1 || (b1 == a1 && b1i < a1i)) {
        float n2; int n2i;
        if (a1 > b2 || (a1 == b2 && a1i < b2i)) { n2 = a1; n2i = a1i; }
        else                                    { n2 = b2; n2i = b2i; }
        sv1[tid] = b1; si1[tid] = b1i; sv2[tid] = n2; si2[tid] = n2i;
      } else {
        if (b1 > a2 || (b1 == a2 && b1i < a2i)) { sv2[tid] = b1; si2[tid] = b1i; }
      }
    }
    __syncthreads();
  }
  const float rowmax = sv1[0];         // approx max: softmax shift only
  const float atop2 = sv2[0];
  __syncthreads();
  // ---- exact rescue: candidates within margin of approx top-2 ----
  const float cutoff = atop2 - 2e-3f;
  if (v0 >= cutoff) { const int p = atomicAdd(&ccnt, 1); if (p < 48) cand[p] = tid; }
  if (v1 >= cutoff) { const int p = atomicAdd(&ccnt, 1); if (p < 48) cand[p] = tid + 256; }
  __syncthreads();
  const int K = min(ccnt, 48);
  if (tid < K) {
    const float* kr = keys + (size_t)cand[tid] * D_;
    float s = 0.f;
    for (int d = 0; d < D_; ++d) s = fmaf(sq[d], kr[d], s);
    cex[tid] = s;
  }
  __syncthreads();
  if (tid == 0) {
    float b1 = -1e30f, b2 = -1e30f; int b1i = 1 << 30, b2i = 1 << 30;
    for (int t = 0; t < K; ++t) {
      const float v = cex[t]; const int idx = cand[t];
      if (v > b1 || (v == b1 && idx < b1i)) { b2 = b1; b2i = b1i; b1 = v; b1i = idx; }
      else if (v > b2 || (v == b2 && idx < b2i)) { b2 = v; b2i = idx; }
    }
    sel1 = b1i; sel2 = b2i; ssat = row[b1i];
  }
  __syncthreads();
  const int i1 = sel1;
  const int i2 = sel2;
  const float s_at_v = ssat;
  // softmax over m, written in place as bf16 hi|lo (row fully read already)
  const float e0 = expf(v0 - rowmax), e1 = expf(v1 - rowmax);
  sv1[tid] = e0 + e1;
  __syncthreads();
  for (int s = 128; s > 0; s >>= 1) {
    if (tid < s) sv1[tid] += sv1[tid + s];
    __syncthreads();
  }
  const float invsum = 1.0f / sv1[0];
  const float p0 = e0 * invsum, p1 = e1 * invsum;
  u16* rs = (u16*)row;
  const u16 h0 = f2bf(p0), h1 = f2bf(p1);
  rs[tid] = h0;
  rs[tid + 256] = h1;
  rs[512 + tid] = f2bf(p0 - bf2f(h0));
  rs[512 + tid + 256] = f2bf(p1 - bf2f(h1));
  __syncthreads();
  // losses (fp32 qf from LDS)
  const float* pos = keys + (size_t)i1 * D_;
  const float* neg = keys + (size_t)i2 * D_;
  float dp = 0.f, dn = 0.f;
  for (int c = tid; c < D_; c += 256) {
    const float qv = sq[c];
    const float dP = qv - pos[c];
    lrow[c] = dP * dP;
    const float a = dP + 1e-6f;
    dp += a * a;
    const float bb = (qv - neg[c]) + 1e-6f;
    dn += bb * bb;
  }
  sv1[tid] = dp; sv2[tid] = dn;
  __syncthreads();
  for (int s = 128; s > 0; s >>= 1) {
    if (tid < s) { sv1[tid] += sv1[tid + s]; sv2[tid] += sv2[tid + s]; }
    __syncthreads();
  }
  if (tid == 0) {
    out2[bn] = fmaxf(sqrtf(sv1[0]) - sqrtf(sv2[0]) + 1.0f, 0.0f);
    out4[bn] = (float)i1;
    s_at[bn] = s_at_v;
    assign[bn] = i1;
  }
}

// K5: qu[b][m][:] = sum_{n: assign=m} exp(s_at[b,n]-colmax[b,m]) * qf[b][n][:]
__global__ __launch_bounds__(256) void k_update_gather(
    const int* __restrict__ assign, const float* __restrict__ s_at,
    const float* __restrict__ colmax, const u16* __restrict__ qf_hl,
    float* __restrict__ qu) {
  const int m = blockIdx.x;
  const int b = blockIdx.y;
  __shared__ int list[4096];
  __shared__ int cnt;
  const int tid = threadIdx.x;
  if (tid == 0) cnt = 0;
  __syncthreads();
  const int* ab = assign + b * N_;
  for (int n = tid; n < N_; n += 256) {
    if (ab[n] == m) { const int p = atomicAdd(&cnt, 1); list[p] = n; }
  }
  __syncthreads();
  const float cm = colmax[b * M_ + m];
  const int c0 = tid, c1 = tid + 256;
  float acc0 = 0.f, acc1 = 0.f;
  const int K = cnt;
  for (int i = 0; i < K; ++i) {
    const int n = list[i];
    const float w = expf(s_at[b * N_ + n] - cm);
    const u16* qrow = qf_hl + ((size_t)b * N_ + n) * 1024;
    acc0 += w * (bf2f(qrow[c0]) + bf2f(qrow[512 + c0]));
    acc1 += w * (bf2f(qrow[c1]) + bf2f(qrow[512 + c1]));
  }
  float* orow = qu + ((size_t)b * M_ + m) * D_;
  orow[c0] = acc0;
  orow[c1] = acc1;
}

// K6 (fused scan): mem[m] = scan over b of l2norm(mem[m] + qu[b][m]), seeded
// from keys. Independent per m -> one launch, loop b inside.
__global__ __launch_bounds__(256) void k_mem_scan(
    const float* __restrict__ qu, const float* __restrict__ keys,
    float* __restrict__ mem) {
  const int m = blockIdx.x;
  const int tid = threadIdx.x;
  const size_t base = (size_t)m * D_;
  float v0 = keys[base + tid], v1 = keys[base + tid + 256];
  __shared__ float red[256];
  for (int b = 0; b < B_; ++b) {
    const float* qb = qu + ((size_t)b * M_ + m) * D_;
    v0 += qb[tid]; v1 += qb[tid + 256];
    red[tid] = v0 * v0 + v1 * v1;
    __syncthreads();
    for (int s = 128; s > 0; s >>= 1) {
      if (tid < s) red[tid] += red[tid + s];
      __syncthreads();
    }
    const float inv = 1.0f / fmaxf(sqrtf(red[0]), 1e-12f);
    __syncthreads();
    v0 *= inv; v1 *= inv;
  }
  mem[base + tid] = v0;
  mem[base + tid + 256] = v1;
}

// K7a: updated_query[:, :512, :, :] = q * inv_norm  (runs LAST: out0 first-half
// region doubles as scratch for keys hi/lo planes earlier in the stream)
__global__ __launch_bounds__(256) void k_out_first(
    const float* __restrict__ q, const float* __restrict__ inv_nrm,
    float* __restrict__ out0) {
  const size_t i4 = (size_t)blockIdx.x * 256 + threadIdx.x;
  const size_t base = i4 * 4;  // flat into q [B,512,4096]
  const int n = (int)(base & 4095);
  const size_t bc = base >> 12;  // b*512 + c
  const size_t b = bc >> 9;
  const float4 v = *(const float4*)(q + base);
  const float4 w = *(const float4*)(inv_nrm + b * N_ + n);
  *(float4*)(out0 + ((bc + b * 512) << 12) + n) =
      make_float4(v.x * w.x, v.y * w.y, v.z * w.z, v.w * w.w);
}

extern "C" void kernel_launch(void* const* d_in, const int* in_sizes, int n_in,
                              void* d_out, int out_size, void* d_ws, size_t ws_size,
                              hipStream_t stream) {
  const float* q = (const float*)d_in[0];     // [8,512,64,64]
  const float* keys = (const float*)d_in[1];  // [512,512]
  float* out = (float*)d_out;
  float* ws = (float*)d_ws;

  u16*   qf_hl   = (u16*)ws;
  float* score   = ws + 16777216;
  float* qu      = ws + 33554432;
  float* inv_nrm = ws + 35651584;
  float* s_at    = ws + 35684352;
  float* colmax  = ws + 35717120;
  int*   assign  = (int*)(ws + 35721216);

  float* out0 = out;             // updated_query  [8,1024,64,64]
  float* out1 = out + 33554432;  // updated_memory [512,512]
  float* out2 = out + 33816576;  // loss_separate  [8,4096]
  float* out3 = out + 33849344;  // loss_compact   [8,4096,512]  (qf32 scratch first)
  float* out4 = out + 50626560;  // closest idx    [8,4096]

  // keys hi/lo planes live in out0's first-half region (k_out_first runs last)
  u16* keys_hl  = (u16*)(out0);              // [512][1024] u16 = 1 MB
  u16* keysT_hl = (u16*)(out0 + 262144);     // [512][1024] u16 = 1 MB

  k_convert_keys<<<dim3(M_), 256, 0, stream>>>(keys, keys_hl, keysT_hl);
  k_norm_transpose<<<dim3(N_ / 32, B_), 256, 0, stream>>>(q, qf_hl, out3,
                                                          inv_nrm);
  k_gemm_split<0><<<dim3(1024), 256, 0, stream>>>(qf_hl, keys_hl, score);
  k_colmax<<<dim3(M_ / 32, B_), 256, 0, stream>>>(score, colmax);
  k_softmax_top2<<<dim3(B_ * N_), 256, 0, stream>>>(score, keys, out2, out3,
                                                    out4, s_at, assign);
  k_update_gather<<<dim3(M_, B_), 256, 0, stream>>>(assign, s_at, colmax,
                                                    qf_hl, qu);
  k_mem_scan<<<dim3(M_), 256, 0, stream>>>(qu, keys, out1);
  k_gemm_split<1><<<dim3(1024), 256, 0, stream>>>((const u16*)score, keysT_hl,
                                                  out0);
  k_out_first<<<dim3((B_ * D_ * HW_ / 4) / 256), 256, 0, stream>>>(q, inv_nrm,
                                                                   out0);
}

// Round 3
// 629.161 us; speedup vs baseline: 1.2836x; 1.2836x over previous
//
#include <hip/hip_runtime.h>
#include <cstdint>
#include <cstddef>

// Problem constants
#define B_  8
#define N_  4096   // H*W
#define M_  512    // memory slots
#define D_  512    // feature dim (= C)
#define HW_ 4096

typedef unsigned short u16;
typedef unsigned int   u32;
typedef unsigned long long u64;
typedef __attribute__((ext_vector_type(8))) __bf16 bf16x8;
typedef __attribute__((ext_vector_type(4))) float  f32x4;

// -------- workspace layout (float offsets), total 143.0 MB --------
// qf_hl  : 0          [B,N,1024] u16  (per row: 512 hi | 512 lo bf16 of l2-normed q)
// score  : 16777216   [B,N,M] f32 raw; after k_softmax_top2 each row becomes
//                     [512 hi | 512 lo] u16 of softmax-over-m (in place)
// qu     : 33554432   [B,M,D] f32
// inv_nrm: 35651584   [B,N]
// s_at   : 35684352   [B,N]  (raw score at argmax = row max)
// colmax : 35717120   [B,M]  (max over n of raw score)
// assign : 35721216   [B,N] int
// keys hi/lo planes live in d_out scratch (out0 first half, rewritten last).
// fp32 qf lives in d_out out3 region (loss_compact overwrites it in K3).

__device__ __forceinline__ u16 f2bf(float x) {
  u32 u = __float_as_uint(x);
  u += 0x7FFFu + ((u >> 16) & 1u);          // RNE
  return (u16)(u >> 16);
}
__device__ __forceinline__ float bf2f(u16 h) {
  return __uint_as_float(((u32)h) << 16);
}

// K0: keys -> hi/lo planes, and transposed hi/lo planes (for the NN concat GEMM)
__global__ __launch_bounds__(256) void k_convert_keys(
    const float* __restrict__ keys, u16* __restrict__ keys_hl,
    u16* __restrict__ keysT_hl) {
  const int m = blockIdx.x;
  const int tid = threadIdx.x;
  for (int d = tid; d < D_; d += 256) {
    const float v = keys[(size_t)m * D_ + d];
    const u16 h = f2bf(v);
    const u16 l = f2bf(v - bf2f(h));
    keys_hl[(size_t)m * 1024 + d] = h;
    keys_hl[(size_t)m * 1024 + 512 + d] = l;
    keysT_hl[(size_t)d * 1024 + m] = h;
    keysT_hl[(size_t)d * 1024 + 512 + m] = l;
  }
}

// K1: l2-normalize over channel + transpose [B,C,N] -> [B,N,(hi|lo)] + fp32 qf
__global__ __launch_bounds__(256) void k_norm_transpose(
    const float* __restrict__ q, u16* __restrict__ qf_hl,
    float* __restrict__ qf32, float* __restrict__ inv_nrm) {
  __shared__ float tile[32][513];
  __shared__ float red[8][32];
  __shared__ float sinv[32];
  const int b = blockIdx.y;
  const int n0 = blockIdx.x * 32;
  const int tid = threadIdx.x;
  const int tx = tid & 31, ty = tid >> 5;
  const float* qb = q + (size_t)b * D_ * HW_ + n0;
  float ss = 0.f;
  for (int c = ty; c < D_; c += 8) {
    const float v = qb[(size_t)c * HW_ + tx];
    tile[tx][c] = v;
    ss += v * v;
  }
  red[ty][tx] = ss;
  __syncthreads();
  if (ty == 0) {
    float s = 0.f;
#pragma unroll
    for (int r = 0; r < 8; ++r) s += red[r][tx];
    const float inv = 1.0f / fmaxf(sqrtf(s), 1e-12f);
    sinv[tx] = inv;
    inv_nrm[b * N_ + n0 + tx] = inv;
  }
  __syncthreads();
  u16* qfb = qf_hl + ((size_t)b * N_ + n0) * 1024;
  float* q32b = qf32 + ((size_t)b * N_ + n0) * D_;
  for (int i = tid; i < 32 * 256; i += 256) {
    const int nl = i >> 8, c2 = (i & 255) << 1;
    const float va = tile[nl][c2] * sinv[nl];
    const float vb = tile[nl][c2 + 1] * sinv[nl];
    const u16 ha = f2bf(va), hb = f2bf(vb);
    const u16 la = f2bf(va - bf2f(ha)), lb = f2bf(vb - bf2f(hb));
    u32* qr = (u32*)(qfb + (size_t)nl * 1024);
    qr[c2 >> 1] = (u32)ha | ((u32)hb << 16);
    qr[256 + (c2 >> 1)] = (u32)la | ((u32)lb << 16);
    *(float2*)&q32b[(size_t)nl * D_ + c2] = make_float2(va, vb);
  }
}

// K2/K7b: split-bf16 MFMA GEMM.  C = (Ah+Al)(Bh+Bl)^T ~= AhBh + AhBl + AlBh.
// A: [rows][512 hi | 512 lo] u16, rows indexed bb*N_+n.  B: [512 rows][hi|lo].
// EPI=0: C row-major fp32 [B*N][M] (score).  EPI=1: transposed write into
// out0 channels 512..1023 via LDS tile.
template <int EPI>
__global__ __launch_bounds__(256) void k_gemm_split(
    const u16* __restrict__ A, const u16* __restrict__ Bg,
    float* __restrict__ C) {
  // XCD-aware mapping: xcd = id&7 owns one batch (32 n-panels x 4 col-tiles),
  // so the 4 col-tiles sharing an A-panel hit the same XCD L2.
  const int g = blockIdx.x;
  const int xcd = g & 7;
  const int s = g >> 3;
  const int panel = xcd * 32 + (s >> 2);   // 0..255
  const int bb = panel >> 5;               // batch
  const int n0 = (panel & 31) * 128;
  const int c0 = (s & 3) * 128;

  const int tid = threadIdx.x;
  const int lane = tid & 63;
  const int wave = tid >> 6;
  const int wr = wave >> 1, wc = wave & 1;
  const int fr = lane & 15;                // frag row (A) / col (B)
  const int kg = lane >> 4;                // k-group 0..3

  __shared__ union __align__(16) {
    u16  st[2][2][128][40];  // [A/B][hi/lo][row][k, padded to 40 (80B: 2-way ok)]
    float tc[64][129];       // EPI=1 transpose tile
  } sh;

  f32x4 acc[4][4] = {};

  const int srow = tid >> 1;   // 0..127 staged row
  const int shf = tid & 1;     // hi/lo plane
  const u16* ga = A + ((size_t)bb * N_ + n0 + srow) * 1024 + shf * 512;
  const u16* gb = Bg + ((size_t)(c0 + srow)) * 1024 + shf * 512;

  uint4 pa0 = *(const uint4*)(ga + 0),  pa1 = *(const uint4*)(ga + 8);
  uint4 pa2 = *(const uint4*)(ga + 16), pa3 = *(const uint4*)(ga + 24);
  uint4 pb0 = *(const uint4*)(gb + 0),  pb1 = *(const uint4*)(gb + 8);
  uint4 pb2 = *(const uint4*)(gb + 16), pb3 = *(const uint4*)(gb + 24);

  for (int k0 = 0; k0 < 512; k0 += 32) {
    __syncthreads();
    *(uint4*)&sh.st[0][shf][srow][0]  = pa0;
    *(uint4*)&sh.st[0][shf][srow][8]  = pa1;
    *(uint4*)&sh.st[0][shf][srow][16] = pa2;
    *(uint4*)&sh.st[0][shf][srow][24] = pa3;
    *(uint4*)&sh.st[1][shf][srow][0]  = pb0;
    *(uint4*)&sh.st[1][shf][srow][8]  = pb1;
    *(uint4*)&sh.st[1][shf][srow][16] = pb2;
    *(uint4*)&sh.st[1][shf][srow][24] = pb3;
    __syncthreads();
    if (k0 + 32 < 512) {  // prefetch next K-slice; hides HBM under the MFMAs
      const u16* gan = ga + k0 + 32;
      const u16* gbn = gb + k0 + 32;
      pa0 = *(const uint4*)(gan + 0);  pa1 = *(const uint4*)(gan + 8);
      pa2 = *(const uint4*)(gan + 16); pa3 = *(const uint4*)(gan + 24);
      pb0 = *(const uint4*)(gbn + 0);  pb1 = *(const uint4*)(gbn + 8);
      pb2 = *(const uint4*)(gbn + 16); pb3 = *(const uint4*)(gbn + 24);
    }
    bf16x8 ah[4], al[4], bh[4], bl[4];
#pragma unroll
    for (int i = 0; i < 4; ++i) {
      ah[i] = *(const bf16x8*)&sh.st[0][0][wr * 64 + i * 16 + fr][kg * 8];
      al[i] = *(const bf16x8*)&sh.st[0][1][wr * 64 + i * 16 + fr][kg * 8];
      bh[i] = *(const bf16x8*)&sh.st[1][0][wc * 64 + i * 16 + fr][kg * 8];
      bl[i] = *(const bf16x8*)&sh.st[1][1][wc * 64 + i * 16 + fr][kg * 8];
    }
#pragma unroll
    for (int i = 0; i < 4; ++i)
#pragma unroll
      for (int j = 0; j < 4; ++j) {
        acc[i][j] = __builtin_amdgcn_mfma_f32_16x16x32_bf16(ah[i], bh[j],
                                                            acc[i][j], 0, 0, 0);
        acc[i][j] = __builtin_amdgcn_mfma_f32_16x16x32_bf16(ah[i], bl[j],
                                                            acc[i][j], 0, 0, 0);
        acc[i][j] = __builtin_amdgcn_mfma_f32_16x16x32_bf16(al[i], bh[j],
                                                            acc[i][j], 0, 0, 0);
      }
  }

  if (EPI == 0) {
    float* Cb = C + ((size_t)bb * N_ + n0 + wr * 64) * M_ + c0 + wc * 64;
#pragma unroll
    for (int i = 0; i < 4; ++i)
#pragma unroll
      for (int j = 0; j < 4; ++j)
#pragma unroll
        for (int r = 0; r < 4; ++r)
          Cb[(size_t)(i * 16 + kg * 4 + r) * M_ + j * 16 + fr] = acc[i][j][r];
  } else {
#pragma unroll
    for (int half = 0; half < 2; ++half) {
      __syncthreads();
      if (wc == half) {
#pragma unroll
        for (int i = 0; i < 4; ++i)
#pragma unroll
          for (int j = 0; j < 4; ++j)
#pragma unroll
            for (int r = 0; r < 4; ++r)
              sh.tc[j * 16 + fr][wr * 64 + i * 16 + kg * 4 + r] = acc[i][j][r];
      }
      __syncthreads();
      float* ob = C + ((size_t)bb * 1024 + 512 + c0 + half * 64) * (size_t)HW_ + n0;
      for (int t = tid; t < 64 * 128; t += 256) {
        const int dl = t >> 7, nl = t & 127;
        ob[(size_t)dl * HW_ + nl] = sh.tc[dl][nl];
      }
    }
  }
}

// K4: colmax[b][m] = max_n score[b][n][m]  (raw scores; runs before K3)
__global__ __launch_bounds__(256) void k_colmax(
    const float* __restrict__ score, float* __restrict__ colmax) {
  const int b = blockIdx.y, m0 = blockIdx.x * 32;
  const int tid = threadIdx.x, tx = tid & 31, ty = tid >> 5;
  const float* sb = score + (size_t)b * N_ * M_ + m0 + tx;
  float mx = -1e30f;
  for (int n = ty; n < N_; n += 8) mx = fmaxf(mx, sb[(size_t)n * M_]);
  __shared__ float red[8][33];
  red[ty][tx] = mx;
  __syncthreads();
  if (ty == 0) {
#pragma unroll
    for (int r = 1; r < 8; ++r) mx = fmaxf(mx, red[r][tx]);
    colmax[b * M_ + m0 + tx] = mx;
  }
}

// K3 (wave-per-row, zero barriers): per (b,n) row, one 64-lane wave.
// Lane owns cols c = lane*8+j (scores + fp32 q, all in registers).
// Approx top-2 via 6-level shfl_xor butterfly (tie: lower index), exact fp32
// rescue of candidates within margin (ballot + serial wave-uniform dots),
// softmax over m written in place as bf16 hi|lo, losses from fp32 q.
// out3 row aliasing is lane-local: each lane reads/writes only its 8 cols.
__global__ __launch_bounds__(256) void k_softmax_top2(
    float* __restrict__ score, const float* __restrict__ keys,
    float* __restrict__ out2, float* out3, float* __restrict__ out4,
    float* __restrict__ s_at, int* __restrict__ assign) {
  const int tid = threadIdx.x;
  const int lane = tid & 63;
  const int bn = blockIdx.x * 4 + (tid >> 6);
  float* row = score + (size_t)bn * M_;
  float* lrow = out3 + (size_t)bn * D_;   // fp32 qf on entry; loss on exit
  const int c0 = lane * 8;

  const float4 va = *(const float4*)(row + c0);
  const float4 vb = *(const float4*)(row + c0 + 4);
  float v[8] = {va.x, va.y, va.z, va.w, vb.x, vb.y, vb.z, vb.w};
  const float4 qa = *(const float4*)(lrow + c0);
  const float4 qb = *(const float4*)(lrow + c0 + 4);
  float qv[8] = {qa.x, qa.y, qa.z, qa.w, qb.x, qb.y, qb.z, qb.w};

  // in-lane top2 (index order; strict > keeps lower index on ties)
  float t1 = v[0], t2 = -3e38f;
  int i1 = c0, i2 = 1 << 30;
#pragma unroll
  for (int j = 1; j < 8; ++j) {
    const int c = c0 + j;
    if (v[j] > t1)      { t2 = t1; i2 = i1; t1 = v[j]; i1 = c; }
    else if (v[j] > t2) { t2 = v[j]; i2 = c; }
  }
  // wave butterfly top2 merge
#pragma unroll
  for (int off = 1; off < 64; off <<= 1) {
    const float p1 = __shfl_xor(t1, off); const int pi1 = __shfl_xor(i1, off);
    const float p2 = __shfl_xor(t2, off); const int pi2 = __shfl_xor(i2, off);
    if (p1 > t1 || (p1 == t1 && pi1 < i1)) {
      // new first = p; second = better of (old first, partner second)
      if (t1 > p2 || (t1 == p2 && i1 < pi2)) { t2 = t1; i2 = i1; }
      else                                   { t2 = p2; i2 = pi2; }
      t1 = p1; i1 = pi1;
    } else {
      if (p1 > t2 || (p1 == t2 && pi1 < i2)) { t2 = p1; i2 = pi1; }
    }
  }
  const float rowmax = t1;   // approx max (softmax shift only)

  // ---- exact fp32 rescue of the selection ----
  const float cutoff = t2 - 2e-3f;
  float b1v = -3e38f, b2v = -3e38f;
  int b1i = 1 << 30, b2i = 1 << 30;
#pragma unroll
  for (int j = 0; j < 8; ++j) {
    u64 mask = __ballot(v[j] >= cutoff);
    while (mask) {
      const int src = (int)__builtin_ctzll(mask);
      mask &= mask - 1;
      const int cidx = src * 8 + j;
      const float* kr = keys + (size_t)cidx * D_ + c0;
      const float4 ka = *(const float4*)(kr);
      const float4 kb = *(const float4*)(kr + 4);
      float s = qv[0] * ka.x;
      s = fmaf(qv[1], ka.y, s); s = fmaf(qv[2], ka.z, s);
      s = fmaf(qv[3], ka.w, s); s = fmaf(qv[4], kb.x, s);
      s = fmaf(qv[5], kb.y, s); s = fmaf(qv[6], kb.z, s);
      s = fmaf(qv[7], kb.w, s);
#pragma unroll
      for (int off = 1; off < 64; off <<= 1) s += __shfl_xor(s, off);
      if (s > b1v || (s == b1v && cidx < b1i)) {
        b2v = b1v; b2i = b1i; b1v = s; b1i = cidx;
      } else if (s > b2v || (s == b2v && cidx < b2i)) {
        b2v = s; b2i = cidx;
      }
    }
  }
  const float s_at_v = row[b1i];   // approx score at exact argmax (pre-overwrite)

  // softmax over m (approx scores), write in place as bf16 hi|lo
  float e[8];
  float sumE = 0.f;
#pragma unroll
  for (int j = 0; j < 8; ++j) { e[j] = expf(v[j] - rowmax); sumE += e[j]; }
#pragma unroll
  for (int off = 1; off < 64; off <<= 1) sumE += __shfl_xor(sumE, off);
  const float invsum = 1.0f / sumE;
  u32 hp[4], lp[4];
#pragma unroll
  for (int jj = 0; jj < 4; ++jj) {
    const float p0 = e[2 * jj] * invsum, p1 = e[2 * jj + 1] * invsum;
    const u16 h0 = f2bf(p0), h1 = f2bf(p1);
    hp[jj] = (u32)h0 | ((u32)h1 << 16);
    lp[jj] = (u32)f2bf(p0 - bf2f(h0)) | ((u32)f2bf(p1 - bf2f(h1)) << 16);
  }
  u16* rs = (u16*)row;
  *(uint4*)(rs + c0) = make_uint4(hp[0], hp[1], hp[2], hp[3]);
  *(uint4*)(rs + 512 + c0) = make_uint4(lp[0], lp[1], lp[2], lp[3]);

  // losses (fp32 q, exact indices)
  const float* pos = keys + (size_t)b1i * D_ + c0;
  const float* neg = keys + (size_t)b2i * D_ + c0;
  const float4 pa = *(const float4*)(pos), pb = *(const float4*)(pos + 4);
  const float4 na = *(const float4*)(neg), nb = *(const float4*)(neg + 4);
  const float pr[8] = {pa.x, pa.y, pa.z, pa.w, pb.x, pb.y, pb.z, pb.w};
  const float nr[8] = {na.x, na.y, na.z, na.w, nb.x, nb.y, nb.z, nb.w};
  float lc[8];
  float dp = 0.f, dn = 0.f;
#pragma unroll
  for (int j = 0; j < 8; ++j) {
    const float dP = qv[j] - pr[j];
    lc[j] = dP * dP;
    const float a = dP + 1e-6f;
    dp = fmaf(a, a, dp);
    const float bb2 = (qv[j] - nr[j]) + 1e-6f;
    dn = fmaf(bb2, bb2, dn);
  }
  *(float4*)(lrow + c0) = make_float4(lc[0], lc[1], lc[2], lc[3]);
  *(float4*)(lrow + c0 + 4) = make_float4(lc[4], lc[5], lc[6], lc[7]);
#pragma unroll
  for (int off = 1; off < 64; off <<= 1) {
    dp += __shfl_xor(dp, off);
    dn += __shfl_xor(dn, off);
  }
  if (lane == 0) {
    out2[bn] = fmaxf(sqrtf(dp) - sqrtf(dn) + 1.0f, 0.0f);
    out4[bn] = (float)b1i;
    s_at[bn] = s_at_v;
    assign[bn] = b1i;
  }
}

// K5: qu[b][m][:] = sum_{n: assign=m} exp(s_at[b,n]-colmax[b,m]) * qf[b][n][:]
__global__ __launch_bounds__(256) void k_update_gather(
    const int* __restrict__ assign, const float* __restrict__ s_at,
    const float* __restrict__ colmax, const u16* __restrict__ qf_hl,
    float* __restrict__ qu) {
  const int m = blockIdx.x;
  const int b = blockIdx.y;
  __shared__ int list[4096];
  __shared__ int cnt;
  const int tid = threadIdx.x;
  if (tid == 0) cnt = 0;
  __syncthreads();
  const int* ab = assign + b * N_;
  for (int n = tid; n < N_; n += 256) {
    if (ab[n] == m) { const int p = atomicAdd(&cnt, 1); list[p] = n; }
  }
  __syncthreads();
  const float cm = colmax[b * M_ + m];
  const int c0 = tid, c1 = tid + 256;
  float acc0 = 0.f, acc1 = 0.f;
  const int K = cnt;
  for (int i = 0; i < K; ++i) {
    const int n = list[i];
    const float w = expf(s_at[b * N_ + n] - cm);
    const u16* qrow = qf_hl + ((size_t)b * N_ + n) * 1024;
    acc0 += w * (bf2f(qrow[c0]) + bf2f(qrow[512 + c0]));
    acc1 += w * (bf2f(qrow[c1]) + bf2f(qrow[512 + c1]));
  }
  float* orow = qu + ((size_t)b * M_ + m) * D_;
  orow[c0] = acc0;
  orow[c1] = acc1;
}

// K6 (fused scan): mem[m] = scan over b of l2norm(mem[m] + qu[b][m]), seeded
// from keys. Independent per m -> one launch, loop b inside.
__global__ __launch_bounds__(256) void k_mem_scan(
    const float* __restrict__ qu, const float* __restrict__ keys,
    float* __restrict__ mem) {
  const int m = blockIdx.x;
  const int tid = threadIdx.x;
  const size_t base = (size_t)m * D_;
  float v0 = keys[base + tid], v1 = keys[base + tid + 256];
  __shared__ float red[256];
  for (int b = 0; b < B_; ++b) {
    const float* qb = qu + ((size_t)b * M_ + m) * D_;
    v0 += qb[tid]; v1 += qb[tid + 256];
    red[tid] = v0 * v0 + v1 * v1;
    __syncthreads();
    for (int s = 128; s > 0; s >>= 1) {
      if (tid < s) red[tid] += red[tid + s];
      __syncthreads();
    }
    const float inv = 1.0f / fmaxf(sqrtf(red[0]), 1e-12f);
    __syncthreads();
    v0 *= inv; v1 *= inv;
  }
  mem[base + tid] = v0;
  mem[base + tid + 256] = v1;
}

// K7a: updated_query[:, :512, :, :] = q * inv_norm  (runs LAST: out0 first-half
// region doubles as scratch for keys hi/lo planes earlier in the stream)
__global__ __launch_bounds__(256) void k_out_first(
    const float* __restrict__ q, const float* __restrict__ inv_nrm,
    float* __restrict__ out0) {
  const size_t i4 = (size_t)blockIdx.x * 256 + threadIdx.x;
  const size_t base = i4 * 4;  // flat into q [B,512,4096]
  const int n = (int)(base & 4095);
  const size_t bc = base >> 12;  // b*512 + c
  const size_t b = bc >> 9;
  const float4 v = *(const float4*)(q + base);
  const float4 w = *(const float4*)(inv_nrm + b * N_ + n);
  *(float4*)(out0 + ((bc + b * 512) << 12) + n) =
      make_float4(v.x * w.x, v.y * w.y, v.z * w.z, v.w * w.w);
}

extern "C" void kernel_launch(void* const* d_in, const int* in_sizes, int n_in,
                              void* d_out, int out_size, void* d_ws, size_t ws_size,
                              hipStream_t stream) {
  const float* q = (const float*)d_in[0];     // [8,512,64,64]
  const float* keys = (const float*)d_in[1];  // [512,512]
  float* out = (float*)d_out;
  float* ws = (float*)d_ws;

  u16*   qf_hl   = (u16*)ws;
  float* score   = ws + 16777216;
  float* qu      = ws + 33554432;
  float* inv_nrm = ws + 35651584;
  float* s_at    = ws + 35684352;
  float* colmax  = ws + 35717120;
  int*   assign  = (int*)(ws + 35721216);

  float* out0 = out;             // updated_query  [8,1024,64,64]
  float* out1 = out + 33554432;  // updated_memory [512,512]
  float* out2 = out + 33816576;  // loss_separate  [8,4096]
  float* out3 = out + 33849344;  // loss_compact   [8,4096,512]  (qf32 scratch first)
  float* out4 = out + 50626560;  // closest idx    [8,4096]

  // keys hi/lo planes live in out0's first-half region (k_out_first runs last)
  u16* keys_hl  = (u16*)(out0);              // [512][1024] u16 = 1 MB
  u16* keysT_hl = (u16*)(out0 + 262144);     // [512][1024] u16 = 1 MB

  k_convert_keys<<<dim3(M_), 256, 0, stream>>>(keys, keys_hl, keysT_hl);
  k_norm_transpose<<<dim3(N_ / 32, B_), 256, 0, stream>>>(q, qf_hl, out3,
                                                          inv_nrm);
  k_gemm_split<0><<<dim3(1024), 256, 0, stream>>>(qf_hl, keys_hl, score);
  k_colmax<<<dim3(M_ / 32, B_), 256, 0, stream>>>(score, colmax);
  k_softmax_top2<<<dim3(B_ * N_ / 4), 256, 0, stream>>>(score, keys, out2, out3,
                                                        out4, s_at, assign);
  k_update_gather<<<dim3(M_, B_), 256, 0, stream>>>(assign, s_at, colmax,
                                                    qf_hl, qu);
  k_mem_scan<<<dim3(M_), 256, 0, stream>>>(qu, keys, out1);
  k_gemm_split<1><<<dim3(1024), 256, 0, stream>>>((const u16*)score, keysT_hl,
                                                  out0);
  k_out_first<<<dim3((B_ * D_ * HW_ / 4) / 256), 256, 0, stream>>>(q, inv_nrm,
                                                                   out0);
}

// Round 4
// 542.088 us; speedup vs baseline: 1.4898x; 1.1606x over previous
//
#include <hip/hip_runtime.h>
#include <cstdint>
#include <cstddef>

// Problem constants
#define B_  8
#define N_  4096   // H*W
#define M_  512    // memory slots
#define D_  512    // feature dim (= C)
#define HW_ 4096

typedef unsigned short u16;
typedef unsigned int   u32;
typedef unsigned long long u64;
typedef __attribute__((ext_vector_type(8))) __bf16 bf16x8;
typedef __attribute__((ext_vector_type(4))) float  f32x4;

// -------- workspace layout (float offsets), total 143.0 MB --------
// qf_hl  : 0          [B,N,1024] u16  (per row: 512 hi | 512 lo bf16 of l2-normed q)
// score  : 16777216   [B,N,M] f32 raw; after k_softmax_top2 each row becomes
//                     [512 hi | 512 lo] u16 of softmax-over-m (in place)
// qu     : 33554432   [B,M,D] f32  (ALSO: keys hi/lo planes scratch, dead before
//                     k_update_gather writes qu — gemm<1> reordered before it)
// s_at   : 35684352   [B,N]  (approx score at exact argmax)
// colmax : 35717120   [B,M] u32 order-preserving-encoded float (atomicMax)
// assign : 35721216   [B,N] int
// fp32 qf lives in d_out out3 region (loss_compact overwrites it in K3).

__device__ __forceinline__ u16 f2bf(float x) {
  u32 u = __float_as_uint(x);
  u += 0x7FFFu + ((u >> 16) & 1u);          // RNE
  return (u16)(u >> 16);
}
__device__ __forceinline__ float bf2f(u16 h) {
  return __uint_as_float(((u32)h) << 16);
}

// K0: keys -> hi/lo planes + transposed planes; init encoded colmax
__global__ __launch_bounds__(256) void k_convert_keys(
    const float* __restrict__ keys, u16* __restrict__ keys_hl,
    u16* __restrict__ keysT_hl, u32* __restrict__ colmax_enc) {
  const int m = blockIdx.x;
  const int tid = threadIdx.x;
  if (m < 16) colmax_enc[m * 256 + tid] = 0u;  // enc(-inf)-safe floor
  for (int d = tid; d < D_; d += 256) {
    const float v = keys[(size_t)m * D_ + d];
    const u16 h = f2bf(v);
    const u16 l = f2bf(v - bf2f(h));
    keys_hl[(size_t)m * 1024 + d] = h;
    keys_hl[(size_t)m * 1024 + 512 + d] = l;
    keysT_hl[(size_t)d * 1024 + m] = h;
    keysT_hl[(size_t)d * 1024 + 512 + m] = l;
  }
}

// K1: l2-normalize over channel: writes qf hi/lo planes, fp32 qf (into out3
// region), AND out0 first half [b][c][n] = q*inv (k_out_first fused away).
__global__ __launch_bounds__(256) void k_norm_transpose(
    const float* __restrict__ q, u16* __restrict__ qf_hl,
    float* __restrict__ qf32, float* __restrict__ out0) {
  __shared__ float tile[32][513];
  __shared__ float red[8][32];
  __shared__ float sinv[32];
  const int b = blockIdx.y;
  const int n0 = blockIdx.x * 32;
  const int tid = threadIdx.x;
  const int tx = tid & 31, ty = tid >> 5;
  const float* qb = q + (size_t)b * D_ * HW_ + n0;
  float ss = 0.f;
  for (int c = ty; c < D_; c += 8) {
    const float v = qb[(size_t)c * HW_ + tx];
    tile[tx][c] = v;
    ss += v * v;
  }
  red[ty][tx] = ss;
  __syncthreads();
  if (ty == 0) {
    float s = 0.f;
#pragma unroll
    for (int r = 0; r < 8; ++r) s += red[r][tx];
    sinv[tx] = 1.0f / fmaxf(sqrtf(s), 1e-12f);
  }
  __syncthreads();
  // out0 first half, original layout (coalesced 128B per c)
  float* o0 = out0 + (size_t)b * 1024 * HW_ + n0;
  const float inv = sinv[tx];
  for (int c = ty; c < D_; c += 8)
    o0[(size_t)c * HW_ + tx] = tile[tx][c] * inv;
  // transposed hi/lo planes + fp32 qf
  u16* qfb = qf_hl + ((size_t)b * N_ + n0) * 1024;
  float* q32b = qf32 + ((size_t)b * N_ + n0) * D_;
  for (int i = tid; i < 32 * 256; i += 256) {
    const int nl = i >> 8, c2 = (i & 255) << 1;
    const float va = tile[nl][c2] * sinv[nl];
    const float vb = tile[nl][c2 + 1] * sinv[nl];
    const u16 ha = f2bf(va), hb = f2bf(vb);
    const u16 la = f2bf(va - bf2f(ha)), lb = f2bf(vb - bf2f(hb));
    u32* qr = (u32*)(qfb + (size_t)nl * 1024);
    qr[c2 >> 1] = (u32)ha | ((u32)hb << 16);
    qr[256 + (c2 >> 1)] = (u32)la | ((u32)lb << 16);
    *(float2*)&q32b[(size_t)nl * D_ + c2] = make_float2(va, vb);
  }
}

// K2/K7b: split-bf16 MFMA GEMM.  C = (Ah+Al)(Bh+Bl)^T ~= AhBh + AhBl + AlBh.
// EPI=0: C row-major fp32 [B*N][M] via LDS-staged coalesced float4 stores,
//        plus per-column encoded atomicMax into colmax (k_colmax fused away).
// EPI=1: transposed write into out0 channels 512..1023 via LDS tile.
template <int EPI>
__global__ __launch_bounds__(256) void k_gemm_split(
    const u16* __restrict__ A, const u16* __restrict__ Bg,
    float* __restrict__ C, u32* __restrict__ colmax_enc) {
  const int g = blockIdx.x;
  const int xcd = g & 7;
  const int s = g >> 3;
  const int panel = xcd * 32 + (s >> 2);   // 0..255
  const int bb = panel >> 5;               // batch
  const int n0 = (panel & 31) * 128;
  const int c0 = (s & 3) * 128;

  const int tid = threadIdx.x;
  const int lane = tid & 63;
  const int wave = tid >> 6;
  const int wr = wave >> 1, wc = wave & 1;
  const int fr = lane & 15;                // frag row (A) / col (B)
  const int kg = lane >> 4;                // k-group 0..3

  __shared__ union __align__(16) {
    u16  st[2][2][128][40];  // [A/B][hi/lo][row][k pad 40 (80B: 2-way ok)]
    float tc[64][130];       // epilogue staging (130: conflict-free stripes)
  } sh;

  f32x4 acc[4][4] = {};

  const int srow = tid >> 1;   // 0..127 staged row
  const int shf = tid & 1;     // hi/lo plane
  const u16* ga = A + ((size_t)bb * N_ + n0 + srow) * 1024 + shf * 512;
  const u16* gb = Bg + ((size_t)(c0 + srow)) * 1024 + shf * 512;

  uint4 pa0 = *(const uint4*)(ga + 0),  pa1 = *(const uint4*)(ga + 8);
  uint4 pa2 = *(const uint4*)(ga + 16), pa3 = *(const uint4*)(ga + 24);
  uint4 pb0 = *(const uint4*)(gb + 0),  pb1 = *(const uint4*)(gb + 8);
  uint4 pb2 = *(const uint4*)(gb + 16), pb3 = *(const uint4*)(gb + 24);

  for (int k0 = 0; k0 < 512; k0 += 32) {
    __syncthreads();
    *(uint4*)&sh.st[0][shf][srow][0]  = pa0;
    *(uint4*)&sh.st[0][shf][srow][8]  = pa1;
    *(uint4*)&sh.st[0][shf][srow][16] = pa2;
    *(uint4*)&sh.st[0][shf][srow][24] = pa3;
    *(uint4*)&sh.st[1][shf][srow][0]  = pb0;
    *(uint4*)&sh.st[1][shf][srow][8]  = pb1;
    *(uint4*)&sh.st[1][shf][srow][16] = pb2;
    *(uint4*)&sh.st[1][shf][srow][24] = pb3;
    __syncthreads();
    if (k0 + 32 < 512) {  // prefetch next K-slice; hides HBM under the MFMAs
      const u16* gan = ga + k0 + 32;
      const u16* gbn = gb + k0 + 32;
      pa0 = *(const uint4*)(gan + 0);  pa1 = *(const uint4*)(gan + 8);
      pa2 = *(const uint4*)(gan + 16); pa3 = *(const uint4*)(gan + 24);
      pb0 = *(const uint4*)(gbn + 0);  pb1 = *(const uint4*)(gbn + 8);
      pb2 = *(const uint4*)(gbn + 16); pb3 = *(const uint4*)(gbn + 24);
    }
    bf16x8 ah[4], al[4];
#pragma unroll
    for (int i = 0; i < 4; ++i) {
      ah[i] = *(const bf16x8*)&sh.st[0][0][wr * 64 + i * 16 + fr][kg * 8];
      al[i] = *(const bf16x8*)&sh.st[0][1][wr * 64 + i * 16 + fr][kg * 8];
    }
#pragma unroll
    for (int j = 0; j < 4; ++j) {
      const bf16x8 bh = *(const bf16x8*)&sh.st[1][0][wc * 64 + j * 16 + fr][kg * 8];
      const bf16x8 bl = *(const bf16x8*)&sh.st[1][1][wc * 64 + j * 16 + fr][kg * 8];
#pragma unroll
      for (int i = 0; i < 4; ++i)
        acc[i][j] = __builtin_amdgcn_mfma_f32_16x16x32_bf16(ah[i], bh,
                                                            acc[i][j], 0, 0, 0);
#pragma unroll
      for (int i = 0; i < 4; ++i)
        acc[i][j] = __builtin_amdgcn_mfma_f32_16x16x32_bf16(ah[i], bl,
                                                            acc[i][j], 0, 0, 0);
#pragma unroll
      for (int i = 0; i < 4; ++i)
        acc[i][j] = __builtin_amdgcn_mfma_f32_16x16x32_bf16(al[i], bh,
                                                            acc[i][j], 0, 0, 0);
    }
  }

  if (EPI == 0) {
    // fused colmax: per-column max over this tile -> encoded atomicMax
#pragma unroll
    for (int j = 0; j < 4; ++j) {
      float mx = -3e38f;
#pragma unroll
      for (int i = 0; i < 4; ++i)
#pragma unroll
        for (int r = 0; r < 4; ++r) mx = fmaxf(mx, acc[i][j][r]);
      mx = fmaxf(mx, __shfl_xor(mx, 16));
      mx = fmaxf(mx, __shfl_xor(mx, 32));
      if (kg == 0) {
        const u32 u = __float_as_uint(mx);
        const u32 enc = (u & 0x80000000u) ? ~u : (u | 0x80000000u);
        atomicMax(colmax_enc + bb * M_ + c0 + wc * 64 + j * 16 + fr, enc);
      }
    }
    // LDS-staged coalesced store (64-row halves)
#pragma unroll
    for (int half = 0; half < 2; ++half) {
      __syncthreads();
      if (wr == half) {
#pragma unroll
        for (int i = 0; i < 4; ++i)
#pragma unroll
          for (int j = 0; j < 4; ++j)
#pragma unroll
            for (int r = 0; r < 4; ++r)
              sh.tc[i * 16 + kg * 4 + r][wc * 64 + j * 16 + fr] = acc[i][j][r];
      }
      __syncthreads();
      float* Cb = C + ((size_t)bb * N_ + n0 + half * 64) * M_ + c0;
      for (int t = tid; t < 64 * 32; t += 256) {
        const int rl = t >> 5, cc = (t & 31) << 2;
        *(float4*)(Cb + (size_t)rl * M_ + cc) = *(const float4*)&sh.tc[rl][cc];
      }
    }
  } else {
#pragma unroll
    for (int half = 0; half < 2; ++half) {
      __syncthreads();
      if (wc == half) {
#pragma unroll
        for (int i = 0; i < 4; ++i)
#pragma unroll
          for (int j = 0; j < 4; ++j)
#pragma unroll
            for (int r = 0; r < 4; ++r)
              sh.tc[j * 16 + fr][wr * 64 + i * 16 + kg * 4 + r] = acc[i][j][r];
      }
      __syncthreads();
      float* ob = C + ((size_t)bb * 1024 + 512 + c0 + half * 64) * (size_t)HW_ + n0;
      for (int t = tid; t < 64 * 128; t += 256) {
        const int dl = t >> 7, nl = t & 127;
        ob[(size_t)dl * HW_ + nl] = sh.tc[dl][nl];
      }
    }
  }
}

// K3 (wave-per-row, zero barriers): approx top-2 via shfl butterfly, exact
// fp32 rescue of the selection, softmax written in place as bf16 hi|lo,
// losses from fp32 qf (out3 aliasing is lane-local).
__global__ __launch_bounds__(256) void k_softmax_top2(
    float* __restrict__ score, const float* __restrict__ keys,
    float* __restrict__ out2, float* out3, float* __restrict__ out4,
    float* __restrict__ s_at, int* __restrict__ assign) {
  const int tid = threadIdx.x;
  const int lane = tid & 63;
  const int bn = blockIdx.x * 4 + (tid >> 6);
  float* row = score + (size_t)bn * M_;
  float* lrow = out3 + (size_t)bn * D_;   // fp32 qf on entry; loss on exit
  const int c0 = lane * 8;

  const float4 va = *(const float4*)(row + c0);
  const float4 vb = *(const float4*)(row + c0 + 4);
  float v[8] = {va.x, va.y, va.z, va.w, vb.x, vb.y, vb.z, vb.w};
  const float4 qa = *(const float4*)(lrow + c0);
  const float4 qb = *(const float4*)(lrow + c0 + 4);
  float qv[8] = {qa.x, qa.y, qa.z, qa.w, qb.x, qb.y, qb.z, qb.w};

  // in-lane top2 (index order; strict > keeps lower index on ties)
  float t1 = v[0], t2 = -3e38f;
  int i1 = c0, i2 = 1 << 30;
#pragma unroll
  for (int j = 1; j < 8; ++j) {
    const int c = c0 + j;
    if (v[j] > t1)      { t2 = t1; i2 = i1; t1 = v[j]; i1 = c; }
    else if (v[j] > t2) { t2 = v[j]; i2 = c; }
  }
#pragma unroll
  for (int off = 1; off < 64; off <<= 1) {
    const float p1 = __shfl_xor(t1, off); const int pi1 = __shfl_xor(i1, off);
    const float p2 = __shfl_xor(t2, off); const int pi2 = __shfl_xor(i2, off);
    if (p1 > t1 || (p1 == t1 && pi1 < i1)) {
      if (t1 > p2 || (t1 == p2 && i1 < pi2)) { t2 = t1; i2 = i1; }
      else                                   { t2 = p2; i2 = pi2; }
      t1 = p1; i1 = pi1;
    } else {
      if (p1 > t2 || (p1 == t2 && pi1 < i2)) { t2 = p1; i2 = pi1; }
    }
  }
  const float rowmax = t1;   // approx max (softmax shift only)

  // ---- exact fp32 rescue of the selection ----
  const float cutoff = t2 - 2e-3f;
  float b1v = -3e38f, b2v = -3e38f;
  int b1i = 1 << 30, b2i = 1 << 30;
#pragma unroll
  for (int j = 0; j < 8; ++j) {
    u64 mask = __ballot(v[j] >= cutoff);
    while (mask) {
      const int src = (int)__builtin_ctzll(mask);
      mask &= mask - 1;
      const int cidx = src * 8 + j;
      const float* kr = keys + (size_t)cidx * D_ + c0;
      const float4 ka = *(const float4*)(kr);
      const float4 kb = *(const float4*)(kr + 4);
      float s = qv[0] * ka.x;
      s = fmaf(qv[1], ka.y, s); s = fmaf(qv[2], ka.z, s);
      s = fmaf(qv[3], ka.w, s); s = fmaf(qv[4], kb.x, s);
      s = fmaf(qv[5], kb.y, s); s = fmaf(qv[6], kb.z, s);
      s = fmaf(qv[7], kb.w, s);
#pragma unroll
      for (int off = 1; off < 64; off <<= 1) s += __shfl_xor(s, off);
      if (s > b1v || (s == b1v && cidx < b1i)) {
        b2v = b1v; b2i = b1i; b1v = s; b1i = cidx;
      } else if (s > b2v || (s == b2v && cidx < b2i)) {
        b2v = s; b2i = cidx;
      }
    }
  }
  const float s_at_v = row[b1i];   // approx score at exact argmax

  // softmax over m (approx scores), write in place as bf16 hi|lo
  float e[8];
  float sumE = 0.f;
#pragma unroll
  for (int j = 0; j < 8; ++j) { e[j] = expf(v[j] - rowmax); sumE += e[j]; }
#pragma unroll
  for (int off = 1; off < 64; off <<= 1) sumE += __shfl_xor(sumE, off);
  const float invsum = 1.0f / sumE;
  u32 hp[4], lp[4];
#pragma unroll
  for (int jj = 0; jj < 4; ++jj) {
    const float p0 = e[2 * jj] * invsum, p1 = e[2 * jj + 1] * invsum;
    const u16 h0 = f2bf(p0), h1 = f2bf(p1);
    hp[jj] = (u32)h0 | ((u32)h1 << 16);
    lp[jj] = (u32)f2bf(p0 - bf2f(h0)) | ((u32)f2bf(p1 - bf2f(h1)) << 16);
  }
  u16* rs = (u16*)row;
  *(uint4*)(rs + c0) = make_uint4(hp[0], hp[1], hp[2], hp[3]);
  *(uint4*)(rs + 512 + c0) = make_uint4(lp[0], lp[1], lp[2], lp[3]);

  // losses (fp32 q, exact indices)
  const float* pos = keys + (size_t)b1i * D_ + c0;
  const float* neg = keys + (size_t)b2i * D_ + c0;
  const float4 pa = *(const float4*)(pos), pb = *(const float4*)(pos + 4);
  const float4 na = *(const float4*)(neg), nb = *(const float4*)(neg + 4);
  const float pr[8] = {pa.x, pa.y, pa.z, pa.w, pb.x, pb.y, pb.z, pb.w};
  const float nr[8] = {na.x, na.y, na.z, na.w, nb.x, nb.y, nb.z, nb.w};
  float lc[8];
  float dp = 0.f, dn = 0.f;
#pragma unroll
  for (int j = 0; j < 8; ++j) {
    const float dP = qv[j] - pr[j];
    lc[j] = dP * dP;
    const float a = dP + 1e-6f;
    dp = fmaf(a, a, dp);
    const float bb2 = (qv[j] - nr[j]) + 1e-6f;
    dn = fmaf(bb2, bb2, dn);
  }
  *(float4*)(lrow + c0) = make_float4(lc[0], lc[1], lc[2], lc[3]);
  *(float4*)(lrow + c0 + 4) = make_float4(lc[4], lc[5], lc[6], lc[7]);
#pragma unroll
  for (int off = 1; off < 64; off <<= 1) {
    dp += __shfl_xor(dp, off);
    dn += __shfl_xor(dn, off);
  }
  if (lane == 0) {
    out2[bn] = fmaxf(sqrtf(dp) - sqrtf(dn) + 1.0f, 0.0f);
    out4[bn] = (float)b1i;
    s_at[bn] = s_at_v;
    assign[bn] = b1i;
  }
}

// K5: qu[b][m][:] = sum_{n: assign=m} exp(s_at[b,n]-colmax[b,m]) * qf[b][n][:]
__global__ __launch_bounds__(256) void k_update_gather(
    const int* __restrict__ assign, const float* __restrict__ s_at,
    const u32* __restrict__ colmax_enc, const u16* __restrict__ qf_hl,
    float* __restrict__ qu) {
  const int m = blockIdx.x;
  const int b = blockIdx.y;
  __shared__ int list[4096];
  __shared__ int cnt;
  const int tid = threadIdx.x;
  if (tid == 0) cnt = 0;
  __syncthreads();
  const int* ab = assign + b * N_;
  for (int n = tid; n < N_; n += 256) {
    if (ab[n] == m) { const int p = atomicAdd(&cnt, 1); list[p] = n; }
  }
  __syncthreads();
  const u32 e = colmax_enc[b * M_ + m];
  const float cm = __uint_as_float((e & 0x80000000u) ? (e ^ 0x80000000u) : ~e);
  const int c0 = tid, c1 = tid + 256;
  float acc0 = 0.f, acc1 = 0.f;
  const int K = cnt;
  for (int i = 0; i < K; ++i) {
    const int n = list[i];
    const float w = expf(s_at[b * N_ + n] - cm);
    const u16* qrow = qf_hl + ((size_t)b * N_ + n) * 1024;
    acc0 += w * (bf2f(qrow[c0]) + bf2f(qrow[512 + c0]));
    acc1 += w * (bf2f(qrow[c1]) + bf2f(qrow[512 + c1]));
  }
  float* orow = qu + ((size_t)b * M_ + m) * D_;
  orow[c0] = acc0;
  orow[c1] = acc1;
}

// K6 (fused scan): mem[m] = scan over b of l2norm(mem[m] + qu[b][m])
__global__ __launch_bounds__(256) void k_mem_scan(
    const float* __restrict__ qu, const float* __restrict__ keys,
    float* __restrict__ mem) {
  const int m = blockIdx.x;
  const int tid = threadIdx.x;
  const size_t base = (size_t)m * D_;
  float v0 = keys[base + tid], v1 = keys[base + tid + 256];
  __shared__ float red[256];
  for (int b = 0; b < B_; ++b) {
    const float* qb = qu + ((size_t)b * M_ + m) * D_;
    v0 += qb[tid]; v1 += qb[tid + 256];
    red[tid] = v0 * v0 + v1 * v1;
    __syncthreads();
    for (int s = 128; s > 0; s >>= 1) {
      if (tid < s) red[tid] += red[tid + s];
      __syncthreads();
    }
    const float inv = 1.0f / fmaxf(sqrtf(red[0]), 1e-12f);
    __syncthreads();
    v0 *= inv; v1 *= inv;
  }
  mem[base + tid] = v0;
  mem[base + tid + 256] = v1;
}

extern "C" void kernel_launch(void* const* d_in, const int* in_sizes, int n_in,
                              void* d_out, int out_size, void* d_ws, size_t ws_size,
                              hipStream_t stream) {
  const float* q = (const float*)d_in[0];     // [8,512,64,64]
  const float* keys = (const float*)d_in[1];  // [512,512]
  float* out = (float*)d_out;
  float* ws = (float*)d_ws;

  u16*   qf_hl   = (u16*)ws;
  float* score   = ws + 16777216;
  float* qu      = ws + 33554432;
  float* s_at    = ws + 35684352;
  u32*   colmax  = (u32*)(ws + 35717120);
  int*   assign  = (int*)(ws + 35721216);

  float* out0 = out;             // updated_query  [8,1024,64,64]
  float* out1 = out + 33554432;  // updated_memory [512,512]
  float* out2 = out + 33816576;  // loss_separate  [8,4096]
  float* out3 = out + 33849344;  // loss_compact   [8,4096,512]  (qf32 scratch first)
  float* out4 = out + 50626560;  // closest idx    [8,4096]

  // keys hi/lo planes live in the qu region (dead before k_update_gather,
  // since gemm<1> is ordered before it)
  u16* keys_hl  = (u16*)qu;                  // [512][1024] u16 = 1 MB
  u16* keysT_hl = (u16*)(qu + 262144);       // [512][1024] u16 = 1 MB

  k_convert_keys<<<dim3(M_), 256, 0, stream>>>(keys, keys_hl, keysT_hl, colmax);
  k_norm_transpose<<<dim3(N_ / 32, B_), 256, 0, stream>>>(q, qf_hl, out3, out0);
  k_gemm_split<0><<<dim3(1024), 256, 0, stream>>>(qf_hl, keys_hl, score, colmax);
  k_softmax_top2<<<dim3(B_ * N_ / 4), 256, 0, stream>>>(score, keys, out2, out3,
                                                        out4, s_at, assign);
  k_gemm_split<1><<<dim3(1024), 256, 0, stream>>>((const u16*)score, keysT_hl,
                                                  out0, nullptr);
  k_update_gather<<<dim3(M_, B_), 256, 0, stream>>>(assign, s_at, colmax,
                                                    qf_hl, qu);
  k_mem_scan<<<dim3(M_), 256, 0, stream>>>(qu, keys, out1);
}

// Round 6
// 497.975 us; speedup vs baseline: 1.6218x; 1.0886x over previous
//
#include <hip/hip_runtime.h>
#include <cstdint>
#include <cstddef>

// Problem constants
#define B_  8
#define N_  4096   // H*W
#define M_  512    // memory slots
#define D_  512    // feature dim (= C)
#define HW_ 4096

typedef unsigned short u16;
typedef unsigned int   u32;
typedef unsigned long long u64;
typedef __attribute__((ext_vector_type(8))) __bf16 bf16x8;
typedef __attribute__((ext_vector_type(4))) float  f32x4;

// -------- workspace layout (float offsets), total 143.0 MB --------
// qf_hl  : 0          [B,N,1024] u16  (per row: 512 hi | 512 lo bf16 of l2-normed q)
// score  : 16777216   [B,N,M] f32 raw; after k_softmax_top2 the hi half of each
//                     1024-u16 row holds bf16 softmax-over-m (lo half stale)
// qu     : 33554432   [B,M,D] f32  (ALSO: keys bf16 planes scratch, dead before
//                     k_update_gather writes qu — gemm1 ordered before it)
// s_at   : 35684352   [B,N]  (approx score at exact argmax)
// colmax : 35717120   [B,M] u32 order-preserving-encoded float (atomicMax)
// assign : 35721216   [B,N] int
// fp32 qf lives in d_out out3 region (loss_compact overwrites it in K3) —
// REQUIRED for selection fidelity: hi+lo reconstruction (~8e-6 dot error)
// flips a near-tie row whose true gap is ~1e-6 (R1/R5 failures, R2-R4 passes).

__device__ __forceinline__ u16 f2bf(float x) {
  u32 u = __float_as_uint(x);
  u += 0x7FFFu + ((u >> 16) & 1u);          // RNE
  return (u16)(u >> 16);
}
__device__ __forceinline__ float bf2f(u16 h) {
  return __uint_as_float(((u32)h) << 16);
}

// K0: keys -> bf16 hi plane [m][512] + transposed hi plane [d][512]; init colmax
__global__ __launch_bounds__(256) void k_convert_keys(
    const float* __restrict__ keys, u16* __restrict__ keys_h,
    u16* __restrict__ keysT_h, u32* __restrict__ colmax_enc) {
  const int m = blockIdx.x;
  const int tid = threadIdx.x;
  if (m < 16) colmax_enc[m * 256 + tid] = 0u;  // enc floor
  for (int d = tid; d < D_; d += 256) {
    const float v = keys[(size_t)m * D_ + d];
    const u16 h = f2bf(v);
    keys_h[(size_t)m * 512 + d] = h;
    keysT_h[(size_t)d * 512 + m] = h;
  }
}

// K1: l2-normalize over channel: writes qf hi/lo planes, fp32 qf (out3 region),
// AND out0 first half [b][c][n] = q*inv
__global__ __launch_bounds__(256) void k_norm_transpose(
    const float* __restrict__ q, u16* __restrict__ qf_hl,
    float* __restrict__ qf32, float* __restrict__ out0) {
  __shared__ float tile[32][513];
  __shared__ float red[8][32];
  __shared__ float sinv[32];
  const int b = blockIdx.y;
  const int n0 = blockIdx.x * 32;
  const int tid = threadIdx.x;
  const int tx = tid & 31, ty = tid >> 5;
  const float* qb = q + (size_t)b * D_ * HW_ + n0;
  float ss = 0.f;
  for (int c = ty; c < D_; c += 8) {
    const float v = qb[(size_t)c * HW_ + tx];
    tile[tx][c] = v;
    ss += v * v;
  }
  red[ty][tx] = ss;
  __syncthreads();
  if (ty == 0) {
    float s = 0.f;
#pragma unroll
    for (int r = 0; r < 8; ++r) s += red[r][tx];
    sinv[tx] = 1.0f / fmaxf(sqrtf(s), 1e-12f);
  }
  __syncthreads();
  float* o0 = out0 + (size_t)b * 1024 * HW_ + n0;
  const float inv = sinv[tx];
  for (int c = ty; c < D_; c += 8)
    o0[(size_t)c * HW_ + tx] = tile[tx][c] * inv;
  u16* qfb = qf_hl + ((size_t)b * N_ + n0) * 1024;
  float* q32b = qf32 + ((size_t)b * N_ + n0) * D_;
  for (int i = tid; i < 32 * 256; i += 256) {
    const int nl = i >> 8, c2 = (i & 255) << 1;
    const float va = tile[nl][c2] * sinv[nl];
    const float vb = tile[nl][c2 + 1] * sinv[nl];
    const u16 ha = f2bf(va), hb = f2bf(vb);
    const u16 la = f2bf(va - bf2f(ha)), lb = f2bf(vb - bf2f(hb));
    u32* qr = (u32*)(qfb + (size_t)nl * 1024);
    qr[c2 >> 1] = (u32)ha | ((u32)hb << 16);
    qr[256 + (c2 >> 1)] = (u32)la | ((u32)lb << 16);
    *(float2*)&q32b[(size_t)nl * D_ + c2] = make_float2(va, vb);
  }
}

// K2: score GEMM, 2-product split: score = (Ah+Al)*Bh.
// A hi/lo planes [row][1024], B = keys bf16 [m][512].
// Epilogue: fused colmax atomicMax + LDS-staged coalesced f32 store.
__global__ __launch_bounds__(256) void k_gemm_score(
    const u16* __restrict__ A, const u16* __restrict__ Bg,
    float* __restrict__ C, u32* __restrict__ colmax_enc) {
  const int g = blockIdx.x;
  const int xcd = g & 7;
  const int s = g >> 3;
  const int panel = xcd * 32 + (s >> 2);   // 0..255
  const int bb = panel >> 5;
  const int n0 = (panel & 31) * 128;
  const int c0 = (s & 3) * 128;

  const int tid = threadIdx.x;
  const int lane = tid & 63;
  const int wave = tid >> 6;
  const int wr = wave >> 1, wc = wave & 1;
  const int fr = lane & 15;
  const int kg = lane >> 4;

  __shared__ union __align__(16) {
    struct { u16 a[2][128][40]; u16 b[128][40]; } st;  // 80B rows: 2-way reads
    float tc[64][130];
  } sh;

  f32x4 acc[4][4] = {};

  const int srow = tid >> 1;   // A: 0..127 row
  const int shf = tid & 1;     // A: hi/lo plane
  const u16* ga = A + ((size_t)bb * N_ + n0 + srow) * 1024 + shf * 512;
  const int brow = tid & 127, bkh = tid >> 7;   // B: row, k-half
  const u16* gb = Bg + (size_t)(c0 + brow) * 512 + bkh * 16;

  uint4 pa0 = *(const uint4*)(ga + 0),  pa1 = *(const uint4*)(ga + 8);
  uint4 pa2 = *(const uint4*)(ga + 16), pa3 = *(const uint4*)(ga + 24);
  uint4 pb0 = *(const uint4*)(gb + 0),  pb1 = *(const uint4*)(gb + 8);

  for (int k0 = 0; k0 < 512; k0 += 32) {
    __syncthreads();
    *(uint4*)&sh.st.a[shf][srow][0]  = pa0;
    *(uint4*)&sh.st.a[shf][srow][8]  = pa1;
    *(uint4*)&sh.st.a[shf][srow][16] = pa2;
    *(uint4*)&sh.st.a[shf][srow][24] = pa3;
    *(uint4*)&sh.st.b[brow][bkh * 16 + 0] = pb0;
    *(uint4*)&sh.st.b[brow][bkh * 16 + 8] = pb1;
    __syncthreads();
    if (k0 + 32 < 512) {
      const u16* gan = ga + k0 + 32;
      const u16* gbn = gb + k0 + 32;
      pa0 = *(const uint4*)(gan + 0);  pa1 = *(const uint4*)(gan + 8);
      pa2 = *(const uint4*)(gan + 16); pa3 = *(const uint4*)(gan + 24);
      pb0 = *(const uint4*)(gbn + 0);  pb1 = *(const uint4*)(gbn + 8);
    }
    bf16x8 ah[4], al[4];
#pragma unroll
    for (int i = 0; i < 4; ++i) {
      ah[i] = *(const bf16x8*)&sh.st.a[0][wr * 64 + i * 16 + fr][kg * 8];
      al[i] = *(const bf16x8*)&sh.st.a[1][wr * 64 + i * 16 + fr][kg * 8];
    }
#pragma unroll
    for (int j = 0; j < 4; ++j) {
      const bf16x8 bh = *(const bf16x8*)&sh.st.b[wc * 64 + j * 16 + fr][kg * 8];
#pragma unroll
      for (int i = 0; i < 4; ++i)
        acc[i][j] = __builtin_amdgcn_mfma_f32_16x16x32_bf16(ah[i], bh,
                                                            acc[i][j], 0, 0, 0);
#pragma unroll
      for (int i = 0; i < 4; ++i)
        acc[i][j] = __builtin_amdgcn_mfma_f32_16x16x32_bf16(al[i], bh,
                                                            acc[i][j], 0, 0, 0);
    }
  }

  // fused colmax
#pragma unroll
  for (int j = 0; j < 4; ++j) {
    float mx = -3e38f;
#pragma unroll
    for (int i = 0; i < 4; ++i)
#pragma unroll
      for (int r = 0; r < 4; ++r) mx = fmaxf(mx, acc[i][j][r]);
    mx = fmaxf(mx, __shfl_xor(mx, 16));
    mx = fmaxf(mx, __shfl_xor(mx, 32));
    if (kg == 0) {
      const u32 u = __float_as_uint(mx);
      const u32 enc = (u & 0x80000000u) ? ~u : (u | 0x80000000u);
      atomicMax(colmax_enc + bb * M_ + c0 + wc * 64 + j * 16 + fr, enc);
    }
  }
  // LDS-staged coalesced store
#pragma unroll
  for (int half = 0; half < 2; ++half) {
    __syncthreads();
    if (wr == half) {
#pragma unroll
      for (int i = 0; i < 4; ++i)
#pragma unroll
        for (int j = 0; j < 4; ++j)
#pragma unroll
          for (int r = 0; r < 4; ++r)
            sh.tc[i * 16 + kg * 4 + r][wc * 64 + j * 16 + fr] = acc[i][j][r];
    }
    __syncthreads();
    float* Cb = C + ((size_t)bb * N_ + n0 + half * 64) * M_ + c0;
    for (int t = tid; t < 64 * 32; t += 256) {
      const int rl = t >> 5, cc = (t & 31) << 2;
      *(float4*)(Cb + (size_t)rl * M_ + cc) = *(const float4*)&sh.tc[rl][cc];
    }
  }
}

// K7b: concat GEMM, single bf16 product: out = p_h * keysT_h.
// A = softmax hi plane (row stride 1024 u16), B = keysT bf16 [d][512].
__global__ __launch_bounds__(256) void k_gemm_concat(
    const u16* __restrict__ A, const u16* __restrict__ Bg,
    float* __restrict__ C) {
  const int g = blockIdx.x;
  const int xcd = g & 7;
  const int s = g >> 3;
  const int panel = xcd * 32 + (s >> 2);   // 0..255
  const int bb = panel >> 5;
  const int n0 = (panel & 31) * 128;
  const int c0 = (s & 3) * 128;            // d block

  const int tid = threadIdx.x;
  const int lane = tid & 63;
  const int wave = tid >> 6;
  const int wr = wave >> 1, wc = wave & 1;
  const int fr = lane & 15;
  const int kg = lane >> 4;

  __shared__ union __align__(16) {
    struct { u16 a[128][40]; u16 b[128][40]; } st;
    float tc[64][130];
  } sh;

  f32x4 acc[4][4] = {};

  const int arow = tid & 127, akh = tid >> 7;
  const u16* ga = A + ((size_t)bb * N_ + n0 + arow) * 1024 + akh * 16;
  const u16* gb = Bg + (size_t)(c0 + arow) * 512 + akh * 16;

  uint4 pa0 = *(const uint4*)(ga + 0), pa1 = *(const uint4*)(ga + 8);
  uint4 pb0 = *(const uint4*)(gb + 0), pb1 = *(const uint4*)(gb + 8);

  for (int k0 = 0; k0 < 512; k0 += 32) {
    __syncthreads();
    *(uint4*)&sh.st.a[arow][akh * 16 + 0] = pa0;
    *(uint4*)&sh.st.a[arow][akh * 16 + 8] = pa1;
    *(uint4*)&sh.st.b[arow][akh * 16 + 0] = pb0;
    *(uint4*)&sh.st.b[arow][akh * 16 + 8] = pb1;
    __syncthreads();
    if (k0 + 32 < 512) {
      const u16* gan = ga + k0 + 32;
      const u16* gbn = gb + k0 + 32;
      pa0 = *(const uint4*)(gan + 0); pa1 = *(const uint4*)(gan + 8);
      pb0 = *(const uint4*)(gbn + 0); pb1 = *(const uint4*)(gbn + 8);
    }
    bf16x8 af[4];
#pragma unroll
    for (int i = 0; i < 4; ++i)
      af[i] = *(const bf16x8*)&sh.st.a[wr * 64 + i * 16 + fr][kg * 8];
#pragma unroll
    for (int j = 0; j < 4; ++j) {
      const bf16x8 bf = *(const bf16x8*)&sh.st.b[wc * 64 + j * 16 + fr][kg * 8];
#pragma unroll
      for (int i = 0; i < 4; ++i)
        acc[i][j] = __builtin_amdgcn_mfma_f32_16x16x32_bf16(af[i], bf,
                                                            acc[i][j], 0, 0, 0);
    }
  }

#pragma unroll
  for (int half = 0; half < 2; ++half) {
    __syncthreads();
    if (wc == half) {
#pragma unroll
      for (int i = 0; i < 4; ++i)
#pragma unroll
        for (int j = 0; j < 4; ++j)
#pragma unroll
          for (int r = 0; r < 4; ++r)
            sh.tc[j * 16 + fr][wr * 64 + i * 16 + kg * 4 + r] = acc[i][j][r];
    }
    __syncthreads();
    float* ob = C + ((size_t)bb * 1024 + 512 + c0 + half * 64) * (size_t)HW_ + n0;
    for (int t = tid; t < 64 * 128; t += 256) {
      const int dl = t >> 7, nl = t & 127;
      ob[(size_t)dl * HW_ + nl] = sh.tc[dl][nl];
    }
  }
}

// K3 (wave-per-row, zero barriers): approx top-2 via shfl butterfly, EXACT
// fp32 rescue of the selection (fp32 qf from out3 scratch, fp32 keys),
// softmax written in place as bf16 hi plane, losses overwrite out3.
__global__ __launch_bounds__(256) void k_softmax_top2(
    float* __restrict__ score, const float* __restrict__ keys,
    float* __restrict__ out2, float* out3, float* __restrict__ out4,
    float* __restrict__ s_at, int* __restrict__ assign) {
  const int tid = threadIdx.x;
  const int lane = tid & 63;
  const int bn = blockIdx.x * 4 + (tid >> 6);
  float* row = score + (size_t)bn * M_;
  float* lrow = out3 + (size_t)bn * D_;   // fp32 qf on entry; loss on exit
  const int c0 = lane * 8;

  const float4 va = *(const float4*)(row + c0);
  const float4 vb = *(const float4*)(row + c0 + 4);
  float v[8] = {va.x, va.y, va.z, va.w, vb.x, vb.y, vb.z, vb.w};
  const float4 qa = *(const float4*)(lrow + c0);
  const float4 qb = *(const float4*)(lrow + c0 + 4);
  float qv[8] = {qa.x, qa.y, qa.z, qa.w, qb.x, qb.y, qb.z, qb.w};

  // in-lane top2 (strict > keeps lower index on ties)
  float t1 = v[0], t2 = -3e38f;
  int i1 = c0, i2 = 1 << 30;
#pragma unroll
  for (int j = 1; j < 8; ++j) {
    const int c = c0 + j;
    if (v[j] > t1)      { t2 = t1; i2 = i1; t1 = v[j]; i1 = c; }
    else if (v[j] > t2) { t2 = v[j]; i2 = c; }
  }
#pragma unroll
  for (int off = 1; off < 64; off <<= 1) {
    const float p1 = __shfl_xor(t1, off); const int pi1 = __shfl_xor(i1, off);
    const float p2 = __shfl_xor(t2, off); const int pi2 = __shfl_xor(i2, off);
    if (p1 > t1 || (p1 == t1 && pi1 < i1)) {
      if (t1 > p2 || (t1 == p2 && i1 < pi2)) { t2 = t1; i2 = i1; }
      else                                   { t2 = p2; i2 = pi2; }
      t1 = p1; i1 = pi1;
    } else {
      if (p1 > t2 || (p1 == t2 && pi1 < i2)) { t2 = p1; i2 = pi1; }
    }
  }
  const float rowmax = t1;

  // ---- exact rescue: margin covers 2-product approx error (~1.6e-3 rms) ----
  const float cutoff = t2 - 1.5e-2f;
  float b1v = -3e38f, b2v = -3e38f;
  int b1i = 1 << 30, b2i = 1 << 30;
#pragma unroll
  for (int j = 0; j < 8; ++j) {
    u64 mask = __ballot(v[j] >= cutoff);
    while (mask) {
      const int src = (int)__builtin_ctzll(mask);
      mask &= mask - 1;
      const int cidx = src * 8 + j;
      const float* kr = keys + (size_t)cidx * D_ + c0;
      const float4 ka = *(const float4*)(kr);
      const float4 kb = *(const float4*)(kr + 4);
      float sdot = qv[0] * ka.x;
      sdot = fmaf(qv[1], ka.y, sdot); sdot = fmaf(qv[2], ka.z, sdot);
      sdot = fmaf(qv[3], ka.w, sdot); sdot = fmaf(qv[4], kb.x, sdot);
      sdot = fmaf(qv[5], kb.y, sdot); sdot = fmaf(qv[6], kb.z, sdot);
      sdot = fmaf(qv[7], kb.w, sdot);
#pragma unroll
      for (int off = 1; off < 64; off <<= 1) sdot += __shfl_xor(sdot, off);
      if (sdot > b1v || (sdot == b1v && cidx < b1i)) {
        b2v = b1v; b2i = b1i; b1v = sdot; b1i = cidx;
      } else if (sdot > b2v || (sdot == b2v && cidx < b2i)) {
        b2v = sdot; b2i = cidx;
      }
    }
  }
  const float s_at_v = row[b1i];   // approx score at exact argmax

  // softmax over m (approx scores), write in place: bf16 hi plane only
  float e[8];
  float sumE = 0.f;
#pragma unroll
  for (int j = 0; j < 8; ++j) { e[j] = expf(v[j] - rowmax); sumE += e[j]; }
#pragma unroll
  for (int off = 1; off < 64; off <<= 1) sumE += __shfl_xor(sumE, off);
  const float invsum = 1.0f / sumE;
  u32 hp[4];
#pragma unroll
  for (int jj = 0; jj < 4; ++jj) {
    const float p0 = e[2 * jj] * invsum, p1 = e[2 * jj + 1] * invsum;
    hp[jj] = (u32)f2bf(p0) | ((u32)f2bf(p1) << 16);
  }
  u16* rs = (u16*)row;
  *(uint4*)(rs + c0) = make_uint4(hp[0], hp[1], hp[2], hp[3]);

  // losses (fp32 q, exact indices)
  const float* pos = keys + (size_t)b1i * D_ + c0;
  const float* neg = keys + (size_t)b2i * D_ + c0;
  const float4 pa = *(const float4*)(pos), pb = *(const float4*)(pos + 4);
  const float4 na = *(const float4*)(neg), nb = *(const float4*)(neg + 4);
  const float pr[8] = {pa.x, pa.y, pa.z, pa.w, pb.x, pb.y, pb.z, pb.w};
  const float nr[8] = {na.x, na.y, na.z, na.w, nb.x, nb.y, nb.z, nb.w};
  float lc[8];
  float dp = 0.f, dn = 0.f;
#pragma unroll
  for (int j = 0; j < 8; ++j) {
    const float dP = qv[j] - pr[j];
    lc[j] = dP * dP;
    const float a = dP + 1e-6f;
    dp = fmaf(a, a, dp);
    const float bb2 = (qv[j] - nr[j]) + 1e-6f;
    dn = fmaf(bb2, bb2, dn);
  }
  *(float4*)(lrow + c0) = make_float4(lc[0], lc[1], lc[2], lc[3]);
  *(float4*)(lrow + c0 + 4) = make_float4(lc[4], lc[5], lc[6], lc[7]);
#pragma unroll
  for (int off = 1; off < 64; off <<= 1) {
    dp += __shfl_xor(dp, off);
    dn += __shfl_xor(dn, off);
  }
  if (lane == 0) {
    out2[bn] = fmaxf(sqrtf(dp) - sqrtf(dn) + 1.0f, 0.0f);
    out4[bn] = (float)b1i;
    s_at[bn] = s_at_v;
    assign[bn] = b1i;
  }
}

// K5: qu[b][m][:] = sum_{n: assign=m} exp(s_at[b,n]-colmax[b,m]) * qf[b][n][:]
__global__ __launch_bounds__(256) void k_update_gather(
    const int* __restrict__ assign, const float* __restrict__ s_at,
    const u32* __restrict__ colmax_enc, const u16* __restrict__ qf_hl,
    float* __restrict__ qu) {
  const int m = blockIdx.x;
  const int b = blockIdx.y;
  __shared__ int list[4096];
  __shared__ int cnt;
  const int tid = threadIdx.x;
  if (tid == 0) cnt = 0;
  __syncthreads();
  const int* ab = assign + b * N_;
  for (int n = tid; n < N_; n += 256) {
    if (ab[n] == m) { const int p = atomicAdd(&cnt, 1); list[p] = n; }
  }
  __syncthreads();
  const u32 e = colmax_enc[b * M_ + m];
  const float cm = __uint_as_float((e & 0x80000000u) ? (e ^ 0x80000000u) : ~e);
  const int c0 = tid, c1 = tid + 256;
  float acc0 = 0.f, acc1 = 0.f;
  const int K = cnt;
  for (int i = 0; i < K; ++i) {
    const int n = list[i];
    const float w = expf(s_at[b * N_ + n] - cm);
    const u16* qrow = qf_hl + ((size_t)b * N_ + n) * 1024;
    acc0 += w * (bf2f(qrow[c0]) + bf2f(qrow[512 + c0]));
    acc1 += w * (bf2f(qrow[c1]) + bf2f(qrow[512 + c1]));
  }
  float* orow = qu + ((size_t)b * M_ + m) * D_;
  orow[c0] = acc0;
  orow[c1] = acc1;
}

// K6 (fused scan): mem[m] = scan over b of l2norm(mem[m] + qu[b][m])
__global__ __launch_bounds__(256) void k_mem_scan(
    const float* __restrict__ qu, const float* __restrict__ keys,
    float* __restrict__ mem) {
  const int m = blockIdx.x;
  const int tid = threadIdx.x;
  const size_t base = (size_t)m * D_;
  float v0 = keys[base + tid], v1 = keys[base + tid + 256];
  __shared__ float red[256];
  for (int b = 0; b < B_; ++b) {
    const float* qb = qu + ((size_t)b * M_ + m) * D_;
    v0 += qb[tid]; v1 += qb[tid + 256];
    red[tid] = v0 * v0 + v1 * v1;
    __syncthreads();
    for (int s = 128; s > 0; s >>= 1) {
      if (tid < s) red[tid] += red[tid + s];
      __syncthreads();
    }
    const float inv = 1.0f / fmaxf(sqrtf(red[0]), 1e-12f);
    __syncthreads();
    v0 *= inv; v1 *= inv;
  }
  mem[base + tid] = v0;
  mem[base + tid + 256] = v1;
}

extern "C" void kernel_launch(void* const* d_in, const int* in_sizes, int n_in,
                              void* d_out, int out_size, void* d_ws, size_t ws_size,
                              hipStream_t stream) {
  const float* q = (const float*)d_in[0];     // [8,512,64,64]
  const float* keys = (const float*)d_in[1];  // [512,512]
  float* out = (float*)d_out;
  float* ws = (float*)d_ws;

  u16*   qf_hl   = (u16*)ws;
  float* score   = ws + 16777216;
  float* qu      = ws + 33554432;
  float* s_at    = ws + 35684352;
  u32*   colmax  = (u32*)(ws + 35717120);
  int*   assign  = (int*)(ws + 35721216);

  float* out0 = out;             // updated_query  [8,1024,64,64]
  float* out1 = out + 33554432;  // updated_memory [512,512]
  float* out2 = out + 33816576;  // loss_separate  [8,4096]
  float* out3 = out + 33849344;  // loss_compact   [8,4096,512]  (qf32 scratch first)
  float* out4 = out + 50626560;  // closest idx    [8,4096]

  // keys bf16 planes live in the qu region (dead before k_update_gather)
  u16* keys_h  = (u16*)qu;                   // [512][512] u16 = 0.5 MB
  u16* keysT_h = (u16*)(qu + 131072);        // [512][512] u16 = 0.5 MB

  k_convert_keys<<<dim3(M_), 256, 0, stream>>>(keys, keys_h, keysT_h, colmax);
  k_norm_transpose<<<dim3(N_ / 32, B_), 256, 0, stream>>>(q, qf_hl, out3, out0);
  k_gemm_score<<<dim3(1024), 256, 0, stream>>>(qf_hl, keys_h, score, colmax);
  k_softmax_top2<<<dim3(B_ * N_ / 4), 256, 0, stream>>>(score, keys, out2, out3,
                                                        out4, s_at, assign);
  k_gemm_concat<<<dim3(1024), 256, 0, stream>>>((const u16*)score, keysT_h,
                                                out0);
  k_update_gather<<<dim3(M_, B_), 256, 0, stream>>>(assign, s_at, colmax,
                                                    qf_hl, qu);
  k_mem_scan<<<dim3(M_), 256, 0, stream>>>(qu, keys, out1);
}